// Round 7
// baseline (85.349 us; speedup 1.0000x reference)
//
#include <hip/hip_runtime.h>
#include <hip/hip_bf16.h>

typedef float  f32x4 __attribute__((ext_vector_type(4)));
typedef float  f32x8 __attribute__((ext_vector_type(8)));
typedef short  s8v   __attribute__((ext_vector_type(8)));
typedef __bf16 b8v   __attribute__((ext_vector_type(8)));
typedef unsigned int u32;
typedef unsigned short ushort;

#define T_DIM  2048
#define C_DIM  1024

// ---------- helpers ----------

typedef const __attribute__((address_space(1))) u32 gu32;
typedef __attribute__((address_space(3))) u32 lu32;

// async global->LDS, 16B per lane; LDS dest = base + lane*16 (wave-uniform base)
static __device__ __forceinline__ void glds16(const void* g, void* l) {
  __builtin_amdgcn_global_load_lds((gu32*)g, (lu32*)l, 16, 0, 0);
}

static __device__ __forceinline__ b8v ldb8(const ushort* p) {
  return __builtin_bit_cast(b8v, *reinterpret_cast<const s8v*>(p));
}

static __device__ __forceinline__ b8v cvt8(f32x8 v) {
  b8v r;
#pragma unroll
  for (int i = 0; i < 8; ++i) r[i] = (__bf16)v[i];
  return r;
}

static __device__ __forceinline__ ushort bfu(float f) {
  __bf16 h = (__bf16)f;
  return __builtin_bit_cast(ushort, h);
}

static __device__ __forceinline__ f32x4 mfma16(b8v a, b8v b, f32x4 c) {
  return __builtin_amdgcn_mfma_f32_16x16x32_bf16(a, b, c, 0, 0, 0);
}

// ---------- kernel 0: W -> Wt bf16 transposed [3][128][1024] ----------
__global__ __launch_bounds__(256) void wconv(const float* __restrict__ Wq,
                                             const float* __restrict__ Wk,
                                             const float* __restrict__ Wv,
                                             ushort* __restrict__ Wt) {
  __shared__ float lds[64][65];
  const int m  = blockIdx.z;
  const int c0 = blockIdx.x * 64;
  const int h0 = blockIdx.y * 64;
  const float* W = (m == 0) ? Wq : (m == 1) ? Wk : Wv;

  const int cl = threadIdx.x >> 4;
  const int h4 = (threadIdx.x & 15) * 4;
#pragma unroll
  for (int i = 0; i < 4; ++i) {
    int c = cl + i * 16;
    float4 v = *reinterpret_cast<const float4*>(W + (c0 + c) * 128 + h0 + h4);
    lds[c][h4] = v.x; lds[c][h4 + 1] = v.y;
    lds[c][h4 + 2] = v.z; lds[c][h4 + 3] = v.w;
  }
  __syncthreads();
  const int hl = threadIdx.x >> 2;
  const int cs = (threadIdx.x & 3) * 16;
  s8v o0, o1;
#pragma unroll
  for (int i = 0; i < 8; ++i) o0[i] = (short)bfu(lds[cs + i][hl]);
#pragma unroll
  for (int i = 0; i < 8; ++i) o1[i] = (short)bfu(lds[cs + 8 + i][hl]);
  ushort* dst = Wt + (m * 128 + h0 + hl) * C_DIM + c0 + cs;
  *reinterpret_cast<s8v*>(dst) = o0;
  *reinterpret_cast<s8v*>(dst + 8) = o1;
}

// ---------- kernel 1: q/k/v projection (m97-style LDS pipeline) ----------
// grid (256, 3) x 256 thr (4 waves). Block tile: 32 rows x 128 cols, BK=64.
// B staged via global_load_lds (linear LDS + pre-swizzled global source,
// swizzled ds_read). A reg-staged f32->bf16 into padded LDS.
__global__ __launch_bounds__(256) void proj(const float* __restrict__ x,
                                            const ushort* __restrict__ Wt,
                                            ushort* __restrict__ q,
                                            ushort* __restrict__ k,
                                            ushort* __restrict__ vt) {
  __shared__ __align__(16) ushort Ab[2][32 * 72];
  __shared__ __align__(16) ushort Bb[2][128 * 64];
  __shared__ __align__(16) ushort stage[5120];

  const int t   = threadIdx.x;
  const int w   = t >> 6;
  const int lid = t & 63;
  const int lr  = lid & 15;
  const int g   = lid >> 4;
  const int wr  = w >> 1;
  const int wc  = w & 1;
  const int m   = blockIdx.y;
  const int r0  = blockIdx.x * 32;

  const int arow = t >> 3;
  const int acol = (t & 7) * 8;
  const float* ag = x + (r0 + arow) * C_DIM + acol;

  const int bswz = (((lid & 7) ^ (lid >> 3)) << 4);
  const char* bg = (const char*)(Wt + m * 128 * C_DIM);

  f32x4 acc[4] = {};

  // ---- prologue: stage K-step 0 ----
#pragma unroll
  for (int j = 0; j < 4; ++j) {
    int h = j * 32 + w * 8 + (lid >> 3);
    glds16(bg + h * 2048 + bswz, (char*)&Bb[0][0] + j * 4096 + w * 1024);
  }
  {
    f32x8 av = *reinterpret_cast<const f32x8*>(ag);
    b8v ac = cvt8(av);
    *reinterpret_cast<s8v*>(&Ab[0][arow * 72 + acol]) =
        __builtin_bit_cast(s8v, ac);
  }
  __syncthreads();

  int cur = 0;
#pragma unroll 1
  for (int i = 0; i < 16; ++i) {
    const int nxt = cur ^ 1;
    f32x8 an;
    if (i < 15) {
      const int kk = (i + 1) * 64;
#pragma unroll
      for (int j = 0; j < 4; ++j) {
        int h = j * 32 + w * 8 + (lid >> 3);
        glds16(bg + h * 2048 + kk * 2 + bswz,
               (char*)&Bb[nxt][0] + j * 4096 + w * 1024);
      }
      an = *reinterpret_cast<const f32x8*>(ag + kk);
    }

#pragma unroll
    for (int kk2 = 0; kk2 < 2; ++kk2) {
      b8v af = ldb8(&Ab[cur][(wr * 16 + lr) * 72 + kk2 * 32 + g * 8]);
#pragma unroll
      for (int cn = 0; cn < 4; ++cn) {
        int h = wc * 64 + cn * 16 + lr;
        int inner = (kk2 * 64 + g * 16) ^ ((h & 7) << 4);
        b8v bf = ldb8(
            (const ushort*)((const char*)&Bb[cur][h * 64] + inner));
        acc[cn] = mfma16(af, bf, acc[cn]);
      }
    }

    if (i < 15) {
      b8v anc = cvt8(an);
      *reinterpret_cast<s8v*>(&Ab[nxt][arow * 72 + acol]) =
          __builtin_bit_cast(s8v, anc);
    }
    __syncthreads();
    cur = nxt;
  }

  // ---- epilogue ----
  if (m < 2) {
#pragma unroll
    for (int cn = 0; cn < 4; ++cn)
#pragma unroll
      for (int j = 0; j < 4; ++j)
        stage[(wr * 16 + 4 * g + j) * 136 + wc * 64 + cn * 16 + lr] =
            bfu(acc[cn][j]);
    __syncthreads();
    ushort* dst = (m == 0) ? q : k;
#pragma unroll
    for (int c = 0; c < 2; ++c) {
      int chunk = c * 256 + t;
      int row = chunk >> 4, col8 = chunk & 15;
      s8v v8 = *reinterpret_cast<const s8v*>(&stage[row * 136 + col8 * 8]);
      *reinterpret_cast<s8v*>(&dst[(r0 + row) * 128 + col8 * 8]) = v8;
    }
  } else {
#pragma unroll
    for (int cn = 0; cn < 4; ++cn)
#pragma unroll
      for (int j = 0; j < 4; ++j)
        stage[(wc * 64 + cn * 16 + lr) * 40 + wr * 16 + 4 * g + j] =
            bfu(acc[cn][j]);
    __syncthreads();
    int b = blockIdx.x >> 6;
    int tbase = (blockIdx.x & 63) * 32;
#pragma unroll
    for (int c = 0; c < 2; ++c) {
      int chunk = c * 256 + t;
      int h = chunk >> 2, t8 = chunk & 3;
      s8v v8 = *reinterpret_cast<const s8v*>(&stage[h * 40 + t8 * 8]);
      *reinterpret_cast<s8v*>(&vt[(b * 128 + h) * T_DIM + tbase + t8 * 8]) = v8;
    }
  }
}

// ---------- kernel 2: flash attention, K/V direct L2->reg ----------
// grid (64, 4): 32 q-rows per block, kv streams 0..2048 in steps of 64.
// 8 waves = (wq in {0,1}) x (wh in {0..3}).
// Per iter, per wave: load own K quarter (16 kv rows) + own V quarter
// (32 h cols) straight to registers (L1/L2-resident, 8x b128 batch-issued),
// QK^T 4 MFMA -> exp -> P to double-buffered pbuf (stride 72: 8 lanes per
// 128B slot on the b128 reads = conflict-free) -> ONE barrier -> PV 4 MFMA.
// O columns partitioned by wh -> only l-sums merge at the end.
__global__ __launch_bounds__(512) void attn(const ushort* __restrict__ q,
                                            const ushort* __restrict__ k,
                                            const ushort* __restrict__ vt,
                                            float* __restrict__ out) {
  __shared__ __align__(16) ushort pbuf[2][2][16 * 72];  // [phase][wq]
  __shared__ float lbuf[8][16];

  const int t   = threadIdx.x;
  const int w   = t >> 6;
  const int lid = t & 63;
  const int lr  = lid & 15;
  const int g   = lid >> 4;
  const int wq  = w >> 2;
  const int wh  = w & 3;
  const int b   = blockIdx.y;
  const int t0  = blockIdx.x * 32 + wq * 16;

  const ushort* qp = q + (b * T_DIM + t0) * 128;
  const ushort* kp = k + b * T_DIM * 128;
  const ushort* vp = vt + b * 128 * T_DIM;

  // hoist Q fragments (wave's 16 q-rows x 128)
  b8v aq[4];
#pragma unroll
  for (int kf = 0; kf < 4; ++kf)
    aq[kf] = ldb8(&qp[lr * 128 + kf * 32 + g * 8]);

  float lsum[4] = {0.0f, 0.0f, 0.0f, 0.0f};
  f32x4 of[2] = {};
  const float scale = 0.08838834764831845f;  // 128^-0.5

  // wave-constant row pointers
  const ushort* krow = kp + (wh * 16 + lr) * 128;        // += 64*128 per iter
  const ushort* vrow0 = vp + (wh * 32 + lr) * T_DIM;      // hf=0
  const ushort* vrow1 = vp + (wh * 32 + 16 + lr) * T_DIM; // hf=1

#pragma unroll 1
  for (int i = 0; i < 32; ++i) {
    const int kv0 = i * 64;

    // ---- batched loads: K quarter (4) + V quarter (4) ----
    s8v kfr[4], vfr[4];
#pragma unroll
    for (int kf = 0; kf < 4; ++kf)
      kfr[kf] = *reinterpret_cast<const s8v*>(
          &krow[kv0 * 128 + kf * 32 + g * 8]);
#pragma unroll
    for (int kc = 0; kc < 2; ++kc) {
      vfr[kc] = *reinterpret_cast<const s8v*>(
          &vrow0[kv0 + kc * 32 + g * 8]);
      vfr[2 + kc] = *reinterpret_cast<const s8v*>(
          &vrow1[kv0 + kc * 32 + g * 8]);
    }

    // ---- QK^T: 16q x 16kv ----
    f32x4 s = {};
#pragma unroll
    for (int kf = 0; kf < 4; ++kf)
      s = mfma16(aq[kf], __builtin_bit_cast(b8v, kfr[kf]), s);

    // ---- p = exp(s*scale - 4); lsum; P -> pbuf[i&1][wq] ----
    ushort* pw = &pbuf[i & 1][wq][0];
#pragma unroll
    for (int j = 0; j < 4; ++j) {
      float p = __expf(s[j] * scale - 4.0f);
      lsum[j] += p;
      pw[(4 * g + j) * 72 + wh * 16 + lr] = bfu(p);
    }
    __syncthreads();

    // ---- PV: 16q x 32h over the kv-64 tile ----
    b8v pa0 = ldb8(&pw[lr * 72 + g * 8]);
    b8v pa1 = ldb8(&pw[lr * 72 + 32 + g * 8]);
    of[0] = mfma16(pa0, __builtin_bit_cast(b8v, vfr[0]), of[0]);
    of[0] = mfma16(pa1, __builtin_bit_cast(b8v, vfr[1]), of[0]);
    of[1] = mfma16(pa0, __builtin_bit_cast(b8v, vfr[2]), of[1]);
    of[1] = mfma16(pa1, __builtin_bit_cast(b8v, vfr[3]), of[1]);
  }

  // ---- reduce l over the 16 kv-lanes, publish per-wave sums ----
#pragma unroll
  for (int j = 0; j < 4; ++j) {
    float r = lsum[j];
    r += __shfl_xor(r, 1);
    r += __shfl_xor(r, 2);
    r += __shfl_xor(r, 4);
    r += __shfl_xor(r, 8);
    lsum[j] = r;
  }
  if (lr == 0) {
#pragma unroll
    for (int j = 0; j < 4; ++j) lbuf[w][4 * g + j] = lsum[j];
  }
  __syncthreads();

  float inv[4];
#pragma unroll
  for (int j = 0; j < 4; ++j) {
    int row = 4 * g + j;
    float l = lbuf[wq * 4 + 0][row] + lbuf[wq * 4 + 1][row] +
              lbuf[wq * 4 + 2][row] + lbuf[wq * 4 + 3][row];
    inv[j] = 1.0f / l;
  }
  float* op = out + (b * T_DIM + t0) * 128;
#pragma unroll
  for (int hf = 0; hf < 2; ++hf)
#pragma unroll
    for (int j = 0; j < 4; ++j)
      op[(4 * g + j) * 128 + wh * 32 + hf * 16 + lr] = of[hf][j] * inv[j];
}

// ---------- launcher ----------
extern "C" void kernel_launch(void* const* d_in, const int* in_sizes, int n_in,
                              void* d_out, int out_size, void* d_ws,
                              size_t ws_size, hipStream_t stream) {
  const float* x  = (const float*)d_in[0];
  const float* Wk = (const float*)d_in[1];
  const float* Wq = (const float*)d_in[2];
  const float* Wv = (const float*)d_in[3];
  float* out = (float*)d_out;

  char* ws = (char*)d_ws;
  ushort* Wt  = (ushort*)ws;                       // 0.75 MB
  ushort* qb  = (ushort*)(ws + (1u << 20));        // 2 MB
  ushort* kb  = (ushort*)(ws + 3u * (1u << 20));   // 2 MB
  ushort* vtb = (ushort*)(ws + 5u * (1u << 20));   // 2 MB

  wconv<<<dim3(16, 2, 3), dim3(256), 0, stream>>>(Wq, Wk, Wv, Wt);
  proj<<<dim3(256, 3), dim3(256), 0, stream>>>(x, Wt, qb, kb, vtb);
  attn<<<dim3(64, 4), dim3(512), 0, stream>>>(qb, kb, vtb, out);
}

// Round 9
// 72.698 us; speedup vs baseline: 1.1740x; 1.1740x over previous
//
#include <hip/hip_runtime.h>
#include <hip/hip_bf16.h>

typedef float  f32x4 __attribute__((ext_vector_type(4)));
typedef float  f32x8 __attribute__((ext_vector_type(8)));
typedef short  s8v   __attribute__((ext_vector_type(8)));
typedef __bf16 b8v   __attribute__((ext_vector_type(8)));
typedef unsigned int u32;
typedef unsigned short ushort;

#define T_DIM  2048
#define C_DIM  1024

// ---------- helpers ----------

typedef const __attribute__((address_space(1))) u32 gu32;
typedef __attribute__((address_space(3))) u32 lu32;

// async global->LDS, 16B per lane; LDS dest = uniform base + lane*16
static __device__ __forceinline__ void glds16(const void* g, void* l) {
  __builtin_amdgcn_global_load_lds((gu32*)g, (lu32*)l, 16, 0, 0);
}

static __device__ __forceinline__ b8v ldb8(const ushort* p) {
  return __builtin_bit_cast(b8v, *reinterpret_cast<const s8v*>(p));
}

static __device__ __forceinline__ b8v cvt8(f32x8 v) {
  b8v r;
#pragma unroll
  for (int i = 0; i < 8; ++i) r[i] = (__bf16)v[i];
  return r;
}

static __device__ __forceinline__ ushort bfu(float f) {
  __bf16 h = (__bf16)f;
  return __builtin_bit_cast(ushort, h);
}

static __device__ __forceinline__ f32x4 mfma16(b8v a, b8v b, f32x4 c) {
  return __builtin_amdgcn_mfma_f32_16x16x32_bf16(a, b, c, 0, 0, 0);
}

// raw barrier with counted vmcnt: waits sandwich the barrier so the compiler
// can neither sink prior mem ops below nor hoist later ones above.
#define BAR_VM(N)                                                        \
  asm volatile("s_waitcnt vmcnt(" #N ") lgkmcnt(0)" ::: "memory");       \
  __builtin_amdgcn_s_barrier();                                          \
  asm volatile("" ::: "memory");

#define BAR_LGKM                                                         \
  asm volatile("s_waitcnt lgkmcnt(0)" ::: "memory");                     \
  __builtin_amdgcn_s_barrier();                                          \
  asm volatile("" ::: "memory");

// ---------- kernel 0: W -> Wt bf16 transposed [3][128][1024] ----------
__global__ __launch_bounds__(256) void wconv(const float* __restrict__ Wq,
                                             const float* __restrict__ Wk,
                                             const float* __restrict__ Wv,
                                             ushort* __restrict__ Wt) {
  __shared__ float lds[64][65];
  const int m  = blockIdx.z;
  const int c0 = blockIdx.x * 64;
  const int h0 = blockIdx.y * 64;
  const float* W = (m == 0) ? Wq : (m == 1) ? Wk : Wv;

  const int cl = threadIdx.x >> 4;
  const int h4 = (threadIdx.x & 15) * 4;
#pragma unroll
  for (int i = 0; i < 4; ++i) {
    int c = cl + i * 16;
    float4 v = *reinterpret_cast<const float4*>(W + (c0 + c) * 128 + h0 + h4);
    lds[c][h4] = v.x; lds[c][h4 + 1] = v.y;
    lds[c][h4 + 2] = v.z; lds[c][h4 + 3] = v.w;
  }
  __syncthreads();
  const int hl = threadIdx.x >> 2;
  const int cs = (threadIdx.x & 3) * 16;
  s8v o0, o1;
#pragma unroll
  for (int i = 0; i < 8; ++i) o0[i] = (short)bfu(lds[cs + i][hl]);
#pragma unroll
  for (int i = 0; i < 8; ++i) o1[i] = (short)bfu(lds[cs + 8 + i][hl]);
  ushort* dst = Wt + (m * 128 + h0 + hl) * C_DIM + c0 + cs;
  *reinterpret_cast<s8v*>(dst) = o0;
  *reinterpret_cast<s8v*>(dst + 8) = o1;
}

// ---------- kernel 1: q/k/v projection, counted-vmcnt pipeline ----------
// grid (256, 3) x 256 thr (4 waves). Tile 32 rows x 128 cols, BK=64.
// Bb: 3 LDS buffers (2-deep glds prefetch). Ab: 2 buffers, reg-staged.
// Dynamic LDS 58368 B; epilogue stage aliases the Bb region.
__global__ __launch_bounds__(256) void proj(const float* __restrict__ x,
                                            const ushort* __restrict__ Wt,
                                            ushort* __restrict__ q,
                                            ushort* __restrict__ k,
                                            ushort* __restrict__ vt) {
  extern __shared__ __align__(16) char psm[];
  ushort* Bbb = (ushort*)psm;             // 3 x 8192 ushort (16 KB each)
  ushort* Abb = (ushort*)(psm + 49152);   // 2 x 2304 ushort (4.6 KB each)
  ushort* stage = (ushort*)psm;           // alias, used after the loop

  const int t   = threadIdx.x;
  const int w   = t >> 6;
  const int lid = t & 63;
  const int lr  = lid & 15;
  const int g   = lid >> 4;
  const int wr  = w >> 1;
  const int wc  = w & 1;
  const int m   = blockIdx.y;
  const int r0  = blockIdx.x * 32;

  const int arow = t >> 3;
  const int acol = (t & 7) * 8;
  const float* ag = x + (r0 + arow) * C_DIM + acol;

  const int bswz = (((lid & 7) ^ (lid >> 3)) << 4);
  const char* bg = (const char*)(Wt + m * 128 * C_DIM);

  f32x4 acc[4] = {};

#define PROJ_STAGE(KK, BUF)                                               \
  _Pragma("unroll") for (int j = 0; j < 4; ++j) {                         \
    int h = j * 32 + w * 8 + (lid >> 3);                                  \
    glds16(bg + h * 2048 + (KK) * 2 + bswz,                               \
           psm + (BUF) * 16384 + j * 4096 + w * 1024);                    \
  }

  // ---- prologue: xload(0) first (its wait leaves the glds in flight) ----
  f32x8 an = *reinterpret_cast<const f32x8*>(ag);
  PROJ_STAGE(0, 0)
  PROJ_STAGE(64, 1)
  {
    b8v ac = cvt8(an);
    *reinterpret_cast<s8v*>(&Abb[arow * 72 + acol]) =
        __builtin_bit_cast(s8v, ac);
  }

  int bc = 0;
#pragma unroll 1
  for (int i = 0; i < 16; ++i) {
    BAR_VM(4)  // stage(i) ready in Bbb[bc] + Ab writes visible

    if (i < 15) an = *reinterpret_cast<const f32x8*>(ag + (i + 1) * 64);
    if (i < 14) {
      int bs = bc + 2; if (bs >= 3) bs -= 3;
      PROJ_STAGE((i + 2) * 64, bs)
    }

    // ---- compute on Bbb[bc], Abb[i&1] ----
    const ushort* Bc = Bbb + bc * 8192;
    const ushort* Ac = Abb + (i & 1) * 2304;
#pragma unroll
    for (int kk2 = 0; kk2 < 2; ++kk2) {
      b8v af = ldb8(&Ac[(wr * 16 + lr) * 72 + kk2 * 32 + g * 8]);
      __builtin_amdgcn_s_setprio(1);
#pragma unroll
      for (int cn = 0; cn < 4; ++cn) {
        int h = wc * 64 + cn * 16 + lr;
        int inner = (kk2 * 64 + g * 16) ^ ((h & 7) << 4);
        b8v bf = ldb8((const ushort*)((const char*)(Bc + h * 64) + inner));
        acc[cn] = mfma16(af, bf, acc[cn]);
      }
      __builtin_amdgcn_s_setprio(0);
    }

    if (i < 15) {
      b8v anc = cvt8(an);
      *reinterpret_cast<s8v*>(&Abb[((i + 1) & 1) * 2304 + arow * 72 + acol]) =
          __builtin_bit_cast(s8v, anc);
    }
    ++bc; if (bc == 3) bc = 0;
  }
#undef PROJ_STAGE

  __syncthreads();  // close all Bb reads before stage-alias writes

  // ---- epilogue ----
  if (m < 2) {
#pragma unroll
    for (int cn = 0; cn < 4; ++cn)
#pragma unroll
      for (int j = 0; j < 4; ++j)
        stage[(wr * 16 + 4 * g + j) * 136 + wc * 64 + cn * 16 + lr] =
            bfu(acc[cn][j]);
    __syncthreads();
    ushort* dst = (m == 0) ? q : k;
#pragma unroll
    for (int c = 0; c < 2; ++c) {
      int chunk = c * 256 + t;
      int row = chunk >> 4, col8 = chunk & 15;
      s8v v8 = *reinterpret_cast<const s8v*>(&stage[row * 136 + col8 * 8]);
      *reinterpret_cast<s8v*>(&dst[(r0 + row) * 128 + col8 * 8]) = v8;
    }
  } else {
#pragma unroll
    for (int cn = 0; cn < 4; ++cn)
#pragma unroll
      for (int j = 0; j < 4; ++j)
        stage[(wc * 64 + cn * 16 + lr) * 40 + wr * 16 + 4 * g + j] =
            bfu(acc[cn][j]);
    __syncthreads();
    int b = blockIdx.x >> 6;
    int tbase = (blockIdx.x & 63) * 32;
#pragma unroll
    for (int c = 0; c < 2; ++c) {
      int chunk = c * 256 + t;
      int h = chunk >> 2, t8 = chunk & 3;
      s8v v8 = *reinterpret_cast<const s8v*>(&stage[h * 40 + t8 * 8]);
      *reinterpret_cast<s8v*>(&vt[(b * 128 + h) * T_DIM + tbase + t8 * 8]) = v8;
    }
  }
}

// ---------- kernel 2: flash attention, counted-vmcnt K/V LDS pipeline ----------
// grid (64, 4): 32 q-rows per block, kv 0..2048 in 32 steps of 64.
// 8 waves = (wq in {0,1}) x (wh in {0..3}). Same tiles/swizzles as the
// verified round-6 kernel; only the barrier/wait structure changed:
// per iter: [vmcnt(0);bar] -> issue stage(i+1) -> QK^T -> exp/P ->
// [lgkm(0);bar] -> PV. The K/V DMA overlaps a full iteration of compute.
// Dynamic LDS 70400 B.
__global__ __launch_bounds__(512) void attn(const ushort* __restrict__ q,
                                            const ushort* __restrict__ k,
                                            const ushort* __restrict__ vt,
                                            float* __restrict__ out) {
  extern __shared__ __align__(16) char smem[];
  // Kb[2] @0 (16384 each), Vb[2] @32768 (16384 each),
  // pbuf @65536 ([2 wq][16*68] ushort), lbuf @69888 ([8][16] f32)
  ushort* pb = (ushort*)(smem + 65536) + (threadIdx.x >> 8) * (16 * 68);
  float* lb = (float*)(smem + 69888);

  const int t   = threadIdx.x;
  const int w   = t >> 6;
  const int lid = t & 63;
  const int lr  = lid & 15;
  const int g   = lid >> 4;
  const int wq  = w >> 2;
  const int wh  = w & 3;
  const int b   = blockIdx.y;
  const int t0  = blockIdx.x * 32;

  const ushort* qp = q + (b * T_DIM + t0 + wq * 16) * 128;
  b8v aq[4];
#pragma unroll
  for (int kf = 0; kf < 4; ++kf)
    aq[kf] = ldb8(&qp[lr * 128 + kf * 32 + g * 8]);

  const int kswz = (((lid & 15) ^ ((w & 1) * 4 + (lid >> 4))) << 4);
  const int vswz = (((lid & 7) ^ (lid >> 3)) << 4);
  const char* kgb = (const char*)(k + b * T_DIM * 128);
  const char* vgb = (const char*)(vt + b * 128 * T_DIM);

  float lsum[4] = {0.0f, 0.0f, 0.0f, 0.0f};
  f32x4 of[2] = {};
  const float scale = 0.08838834764831845f;  // 128^-0.5

#define ATTN_STAGE(KV0, BUF)                                              \
  _Pragma("unroll") for (int j = 0; j < 2; ++j) {                         \
    int r = j * 32 + w * 4 + (lid >> 4);                                  \
    glds16(kgb + ((KV0) + r) * 256 + kswz,                                \
           smem + (BUF) * 16384 + j * 8192 + w * 1024);                   \
  }                                                                       \
  _Pragma("unroll") for (int j = 0; j < 2; ++j) {                         \
    int h = j * 64 + w * 8 + (lid >> 3);                                  \
    glds16(vgb + h * 4096 + (KV0) * 2 + vswz,                             \
           smem + 32768 + (BUF) * 16384 + j * 8192 + w * 1024);           \
  }

  // ---- prologue: stage kv-step 0 into buffer 0 ----
  ATTN_STAGE(0, 0)

  int cur = 0;
#pragma unroll 1
  for (int i = 0; i < 32; ++i) {
    BAR_VM(0)  // stage(i) complete on all waves

    if (i < 31) { ATTN_STAGE((i + 1) * 64, cur ^ 1) }

    const ushort* Kb = (const ushort*)(smem + cur * 16384);
    const ushort* Vb = (const ushort*)(smem + 32768 + cur * 16384);

    // ---- QK^T: 16q x 16kv ----
    f32x4 s = {};
    {
      const int r = wh * 16 + lr;
      b8v bk0 = ldb8((const ushort*)((const char*)(Kb + r * 128) +
                                     ((0 * 64 + g * 16) ^ ((r & 7) << 4))));
      b8v bk1 = ldb8((const ushort*)((const char*)(Kb + r * 128) +
                                     ((1 * 64 + g * 16) ^ ((r & 7) << 4))));
      b8v bk2 = ldb8((const ushort*)((const char*)(Kb + r * 128) +
                                     ((2 * 64 + g * 16) ^ ((r & 7) << 4))));
      b8v bk3 = ldb8((const ushort*)((const char*)(Kb + r * 128) +
                                     ((3 * 64 + g * 16) ^ ((r & 7) << 4))));
      __builtin_amdgcn_s_setprio(1);
      s = mfma16(aq[0], bk0, s);
      s = mfma16(aq[1], bk1, s);
      s = mfma16(aq[2], bk2, s);
      s = mfma16(aq[3], bk3, s);
      __builtin_amdgcn_s_setprio(0);
    }

    // ---- p = exp(s*scale - 4); lsum; P -> pbuf ----
#pragma unroll
    for (int j = 0; j < 4; ++j) {
      float p = __expf(s[j] * scale - 4.0f);
      lsum[j] += p;
      pb[(4 * g + j) * 68 + wh * 16 + lr] = bfu(p);
    }

    BAR_LGKM  // P visible; K/V DMA for i+1 stays in flight

    // ---- PV: 16q x 32h over the kv-64 tile ----
    b8v pa0 = ldb8(&pb[lr * 68 + g * 8]);
    b8v pa1 = ldb8(&pb[lr * 68 + 32 + g * 8]);
#pragma unroll
    for (int hf = 0; hf < 2; ++hf) {
      const int h = wh * 32 + hf * 16 + lr;
      int i0 = (g * 16) ^ ((h & 7) << 4);
      int i1 = (64 + g * 16) ^ ((h & 7) << 4);
      b8v v0 = ldb8((const ushort*)((const char*)(Vb + h * 64) + i0));
      b8v v1 = ldb8((const ushort*)((const char*)(Vb + h * 64) + i1));
      __builtin_amdgcn_s_setprio(1);
      of[hf] = mfma16(pa0, v0, of[hf]);
      of[hf] = mfma16(pa1, v1, of[hf]);
      __builtin_amdgcn_s_setprio(0);
    }
    cur ^= 1;
  }
#undef ATTN_STAGE

  // ---- merge l across the 4 wh-quarters ----
#pragma unroll
  for (int j = 0; j < 4; ++j) {
    float r = lsum[j];
    r += __shfl_xor(r, 1);
    r += __shfl_xor(r, 2);
    r += __shfl_xor(r, 4);
    r += __shfl_xor(r, 8);
    lsum[j] = r;
  }
  if (lr == 0) {
#pragma unroll
    for (int j = 0; j < 4; ++j) lb[(wq * 4 + wh) * 16 + 4 * g + j] = lsum[j];
  }
  __syncthreads();

  float inv[4];
#pragma unroll
  for (int j = 0; j < 4; ++j) {
    int row = 4 * g + j;
    float l = lb[(wq * 4 + 0) * 16 + row] + lb[(wq * 4 + 1) * 16 + row] +
              lb[(wq * 4 + 2) * 16 + row] + lb[(wq * 4 + 3) * 16 + row];
    inv[j] = 1.0f / l;
  }
  float* op = out + (b * T_DIM + t0 + wq * 16) * 128;
#pragma unroll
  for (int hf = 0; hf < 2; ++hf)
#pragma unroll
    for (int j = 0; j < 4; ++j)
      op[(4 * g + j) * 128 + wh * 32 + hf * 16 + lr] = of[hf][j] * inv[j];
}

// ---------- launcher ----------
extern "C" void kernel_launch(void* const* d_in, const int* in_sizes, int n_in,
                              void* d_out, int out_size, void* d_ws,
                              size_t ws_size, hipStream_t stream) {
  const float* x  = (const float*)d_in[0];
  const float* Wk = (const float*)d_in[1];
  const float* Wq = (const float*)d_in[2];
  const float* Wv = (const float*)d_in[3];
  float* out = (float*)d_out;

  char* ws = (char*)d_ws;
  ushort* Wt  = (ushort*)ws;                       // 0.75 MB
  ushort* qb  = (ushort*)(ws + (1u << 20));        // 2 MB
  ushort* kb  = (ushort*)(ws + 3u * (1u << 20));   // 2 MB
  ushort* vtb = (ushort*)(ws + 5u * (1u << 20));   // 2 MB

  (void)hipFuncSetAttribute(reinterpret_cast<const void*>(&proj),
                            hipFuncAttributeMaxDynamicSharedMemorySize, 58368);
  (void)hipFuncSetAttribute(reinterpret_cast<const void*>(&attn),
                            hipFuncAttributeMaxDynamicSharedMemorySize, 70400);

  wconv<<<dim3(16, 2, 3), dim3(256), 0, stream>>>(Wq, Wk, Wv, Wt);
  proj<<<dim3(256, 3), dim3(256), 58368, stream>>>(x, Wt, qb, kb, vtb);
  attn<<<dim3(64, 4), dim3(512), 70400, stream>>>(qb, kb, vtb, out);
}

// Round 10
// 64.912 us; speedup vs baseline: 1.3149x; 1.1200x over previous
//
#include <hip/hip_runtime.h>
#include <hip/hip_bf16.h>

typedef float  f32x4 __attribute__((ext_vector_type(4)));
typedef float  f32x8 __attribute__((ext_vector_type(8)));
typedef short  s8v   __attribute__((ext_vector_type(8)));
typedef __bf16 b8v   __attribute__((ext_vector_type(8)));
typedef unsigned int u32;
typedef unsigned short ushort;

#define T_DIM  2048
#define C_DIM  1024

// ---------- helpers ----------

typedef const __attribute__((address_space(1))) u32 gu32;
typedef __attribute__((address_space(3))) u32 lu32;

// async global->LDS, 16B per lane; LDS dest = uniform base + lane*16
static __device__ __forceinline__ void glds16(const void* g, void* l) {
  __builtin_amdgcn_global_load_lds((gu32*)g, (lu32*)l, 16, 0, 0);
}

static __device__ __forceinline__ b8v ldb8(const ushort* p) {
  return __builtin_bit_cast(b8v, *reinterpret_cast<const s8v*>(p));
}

static __device__ __forceinline__ b8v cvt8(f32x8 v) {
  b8v r;
#pragma unroll
  for (int i = 0; i < 8; ++i) r[i] = (__bf16)v[i];
  return r;
}

static __device__ __forceinline__ ushort bfu(float f) {
  __bf16 h = (__bf16)f;
  return __builtin_bit_cast(ushort, h);
}

static __device__ __forceinline__ f32x4 mfma16(b8v a, b8v b, f32x4 c) {
  return __builtin_amdgcn_mfma_f32_16x16x32_bf16(a, b, c, 0, 0, 0);
}

// raw barrier with counted vmcnt
#define BAR_VM(N)                                                        \
  asm volatile("s_waitcnt vmcnt(" #N ") lgkmcnt(0)" ::: "memory");       \
  __builtin_amdgcn_s_barrier();                                          \
  asm volatile("" ::: "memory");

#define BAR_LGKM                                                         \
  asm volatile("s_waitcnt lgkmcnt(0)" ::: "memory");                     \
  __builtin_amdgcn_s_barrier();                                          \
  asm volatile("" ::: "memory");

// ---------- kernel 0: W -> Wt bf16 transposed [3][128][1024] ----------
__global__ __launch_bounds__(256) void wconv(const float* __restrict__ Wq,
                                             const float* __restrict__ Wk,
                                             const float* __restrict__ Wv,
                                             ushort* __restrict__ Wt) {
  __shared__ float lds[64][65];
  const int m  = blockIdx.z;
  const int c0 = blockIdx.x * 64;
  const int h0 = blockIdx.y * 64;
  const float* W = (m == 0) ? Wq : (m == 1) ? Wk : Wv;

  const int cl = threadIdx.x >> 4;
  const int h4 = (threadIdx.x & 15) * 4;
#pragma unroll
  for (int i = 0; i < 4; ++i) {
    int c = cl + i * 16;
    float4 v = *reinterpret_cast<const float4*>(W + (c0 + c) * 128 + h0 + h4);
    lds[c][h4] = v.x; lds[c][h4 + 1] = v.y;
    lds[c][h4 + 2] = v.z; lds[c][h4 + 3] = v.w;
  }
  __syncthreads();
  const int hl = threadIdx.x >> 2;
  const int cs = (threadIdx.x & 3) * 16;
  s8v o0, o1;
#pragma unroll
  for (int i = 0; i < 8; ++i) o0[i] = (short)bfu(lds[cs + i][hl]);
#pragma unroll
  for (int i = 0; i < 8; ++i) o1[i] = (short)bfu(lds[cs + 8 + i][hl]);
  ushort* dst = Wt + (m * 128 + h0 + hl) * C_DIM + c0 + cs;
  *reinterpret_cast<s8v*>(dst) = o0;
  *reinterpret_cast<s8v*>(dst + 8) = o1;
}

// ---------- kernel 1: q/k/v projection (verified round-6 version) ----------
__global__ __launch_bounds__(256) void proj(const float* __restrict__ x,
                                            const ushort* __restrict__ Wt,
                                            ushort* __restrict__ q,
                                            ushort* __restrict__ k,
                                            ushort* __restrict__ vt) {
  __shared__ __align__(16) ushort Ab[2][32 * 72];
  __shared__ __align__(16) ushort Bb[2][128 * 64];
  __shared__ __align__(16) ushort stage[5120];

  const int t   = threadIdx.x;
  const int w   = t >> 6;
  const int lid = t & 63;
  const int lr  = lid & 15;
  const int g   = lid >> 4;
  const int wr  = w >> 1;
  const int wc  = w & 1;
  const int m   = blockIdx.y;
  const int r0  = blockIdx.x * 32;

  const int arow = t >> 3;
  const int acol = (t & 7) * 8;
  const float* ag = x + (r0 + arow) * C_DIM + acol;

  const int bswz = (((lid & 7) ^ (lid >> 3)) << 4);
  const char* bg = (const char*)(Wt + m * 128 * C_DIM);

  f32x4 acc[4] = {};

#pragma unroll
  for (int j = 0; j < 4; ++j) {
    int h = j * 32 + w * 8 + (lid >> 3);
    glds16(bg + h * 2048 + bswz, (char*)&Bb[0][0] + j * 4096 + w * 1024);
  }
  {
    f32x8 av = *reinterpret_cast<const f32x8*>(ag);
    b8v ac = cvt8(av);
    *reinterpret_cast<s8v*>(&Ab[0][arow * 72 + acol]) =
        __builtin_bit_cast(s8v, ac);
  }
  __syncthreads();

  int cur = 0;
#pragma unroll 1
  for (int i = 0; i < 16; ++i) {
    const int nxt = cur ^ 1;
    f32x8 an;
    if (i < 15) {
      const int kk = (i + 1) * 64;
#pragma unroll
      for (int j = 0; j < 4; ++j) {
        int h = j * 32 + w * 8 + (lid >> 3);
        glds16(bg + h * 2048 + kk * 2 + bswz,
               (char*)&Bb[nxt][0] + j * 4096 + w * 1024);
      }
      an = *reinterpret_cast<const f32x8*>(ag + kk);
    }

#pragma unroll
    for (int kk2 = 0; kk2 < 2; ++kk2) {
      b8v af = ldb8(&Ab[cur][(wr * 16 + lr) * 72 + kk2 * 32 + g * 8]);
#pragma unroll
      for (int cn = 0; cn < 4; ++cn) {
        int h = wc * 64 + cn * 16 + lr;
        int inner = (kk2 * 64 + g * 16) ^ ((h & 7) << 4);
        b8v bf = ldb8(
            (const ushort*)((const char*)&Bb[cur][h * 64] + inner));
        acc[cn] = mfma16(af, bf, acc[cn]);
      }
    }

    if (i < 15) {
      b8v anc = cvt8(an);
      *reinterpret_cast<s8v*>(&Ab[nxt][arow * 72 + acol]) =
          __builtin_bit_cast(s8v, anc);
    }
    __syncthreads();
    cur = nxt;
  }

  if (m < 2) {
#pragma unroll
    for (int cn = 0; cn < 4; ++cn)
#pragma unroll
      for (int j = 0; j < 4; ++j)
        stage[(wr * 16 + 4 * g + j) * 136 + wc * 64 + cn * 16 + lr] =
            bfu(acc[cn][j]);
    __syncthreads();
    ushort* dst = (m == 0) ? q : k;
#pragma unroll
    for (int c = 0; c < 2; ++c) {
      int chunk = c * 256 + t;
      int row = chunk >> 4, col8 = chunk & 15;
      s8v v8 = *reinterpret_cast<const s8v*>(&stage[row * 136 + col8 * 8]);
      *reinterpret_cast<s8v*>(&dst[(r0 + row) * 128 + col8 * 8]) = v8;
    }
  } else {
#pragma unroll
    for (int cn = 0; cn < 4; ++cn)
#pragma unroll
      for (int j = 0; j < 4; ++j)
        stage[(wc * 64 + cn * 16 + lr) * 40 + wr * 16 + 4 * g + j] =
            bfu(acc[cn][j]);
    __syncthreads();
    int b = blockIdx.x >> 6;
    int tbase = (blockIdx.x & 63) * 32;
#pragma unroll
    for (int c = 0; c < 2; ++c) {
      int chunk = c * 256 + t;
      int h = chunk >> 2, t8 = chunk & 3;
      s8v v8 = *reinterpret_cast<const s8v*>(&stage[h * 40 + t8 * 8]);
      *reinterpret_cast<s8v*>(&vt[(b * 128 + h) * T_DIM + tbase + t8 * 8]) = v8;
    }
  }
}

// ---------- kernel 2: flash attention, 2-deep counted-vmcnt pipeline ----------
// grid (64, 4): 32 q-rows/block, kv 0..2048 in 32 steps of 64.
// 8 waves = (wq in {0,1}) x (wh in {0..3}). 3 K/V LDS buffers; per wave a
// stage = 4 glds; 2 stages in flight -> steady-state wait vmcnt(4), drain
// only in the peeled final iteration. Tiles/swizzles identical to round 6.
// LDS: Kb[3]@0 (16K each), Vb[3]@49152 (16K each), pbuf@98304, lbuf@102656.
__global__ __launch_bounds__(512) void attn(const ushort* __restrict__ q,
                                            const ushort* __restrict__ k,
                                            const ushort* __restrict__ vt,
                                            float* __restrict__ out) {
  extern __shared__ __align__(16) char smem[];
  ushort* pb = (ushort*)(smem + 98304) + (threadIdx.x >> 8) * (16 * 68);
  float* lb = (float*)(smem + 102656);

  const int t   = threadIdx.x;
  const int w   = t >> 6;
  const int lid = t & 63;
  const int lr  = lid & 15;
  const int g   = lid >> 4;
  const int wq  = w >> 2;
  const int wh  = w & 3;
  const int b   = blockIdx.y;
  const int t0  = blockIdx.x * 32;

  const ushort* qp = q + (b * T_DIM + t0 + wq * 16) * 128;
  b8v aq[4];
#pragma unroll
  for (int kf = 0; kf < 4; ++kf)
    aq[kf] = ldb8(&qp[lr * 128 + kf * 32 + g * 8]);

  const int kswz = (((lid & 15) ^ ((w & 1) * 4 + (lid >> 4))) << 4);
  const int vswz = (((lid & 7) ^ (lid >> 3)) << 4);
  const char* kgb = (const char*)(k + b * T_DIM * 128);
  const char* vgb = (const char*)(vt + b * 128 * T_DIM);

  float lsum[4] = {0.0f, 0.0f, 0.0f, 0.0f};
  f32x4 of[2] = {};
  const float scale = 0.08838834764831845f;  // 128^-0.5

#define ATTN_STAGE(KV0, BUF)                                              \
  _Pragma("unroll") for (int j = 0; j < 2; ++j) {                         \
    int r = j * 32 + w * 4 + (lid >> 4);                                  \
    glds16(kgb + ((KV0) + r) * 256 + kswz,                                \
           smem + (BUF) * 16384 + j * 8192 + w * 1024);                   \
  }                                                                       \
  _Pragma("unroll") for (int j = 0; j < 2; ++j) {                         \
    int h = j * 64 + w * 8 + (lid >> 3);                                  \
    glds16(vgb + h * 4096 + (KV0) * 2 + vswz,                             \
           smem + 49152 + (BUF) * 16384 + j * 8192 + w * 1024);           \
  }

#define ATTN_BODY                                                          \
  {                                                                        \
    const ushort* Kb = (const ushort*)(smem + cur * 16384);                \
    const ushort* Vb = (const ushort*)(smem + 49152 + cur * 16384);        \
    f32x4 s = {};                                                          \
    {                                                                      \
      const int r = wh * 16 + lr;                                          \
      b8v bk0 = ldb8((const ushort*)((const char*)(Kb + r * 128) +         \
                                     ((0 * 64 + g * 16) ^ ((r & 7) << 4)))); \
      b8v bk1 = ldb8((const ushort*)((const char*)(Kb + r * 128) +         \
                                     ((1 * 64 + g * 16) ^ ((r & 7) << 4)))); \
      b8v bk2 = ldb8((const ushort*)((const char*)(Kb + r * 128) +         \
                                     ((2 * 64 + g * 16) ^ ((r & 7) << 4)))); \
      b8v bk3 = ldb8((const ushort*)((const char*)(Kb + r * 128) +         \
                                     ((3 * 64 + g * 16) ^ ((r & 7) << 4)))); \
      __builtin_amdgcn_s_setprio(1);                                       \
      s = mfma16(aq[0], bk0, s);                                           \
      s = mfma16(aq[1], bk1, s);                                           \
      s = mfma16(aq[2], bk2, s);                                           \
      s = mfma16(aq[3], bk3, s);                                           \
      __builtin_amdgcn_s_setprio(0);                                       \
    }                                                                      \
    _Pragma("unroll") for (int j = 0; j < 4; ++j) {                        \
      float p = __expf(s[j] * scale - 4.0f);                               \
      lsum[j] += p;                                                        \
      pb[(4 * g + j) * 68 + wh * 16 + lr] = bfu(p);                        \
    }                                                                      \
    BAR_LGKM                                                               \
    b8v pa0 = ldb8(&pb[lr * 68 + g * 8]);                                  \
    b8v pa1 = ldb8(&pb[lr * 68 + 32 + g * 8]);                             \
    _Pragma("unroll") for (int hf = 0; hf < 2; ++hf) {                     \
      const int h = wh * 32 + hf * 16 + lr;                                \
      int i0 = (g * 16) ^ ((h & 7) << 4);                                  \
      int i1 = (64 + g * 16) ^ ((h & 7) << 4);                             \
      b8v v0 = ldb8((const ushort*)((const char*)(Vb + h * 64) + i0));     \
      b8v v1 = ldb8((const ushort*)((const char*)(Vb + h * 64) + i1));     \
      __builtin_amdgcn_s_setprio(1);                                       \
      of[hf] = mfma16(pa0, v0, of[hf]);                                    \
      of[hf] = mfma16(pa1, v1, of[hf]);                                    \
      __builtin_amdgcn_s_setprio(0);                                       \
    }                                                                      \
  }

  // ---- prologue: 2 stages in flight ----
  ATTN_STAGE(0, 0)
  ATTN_STAGE(64, 1)

  int cur = 0;
#pragma unroll 1
  for (int i = 0; i < 31; ++i) {
    BAR_VM(4)  // oldest stage (i) complete; stage (i+1) still in flight
    if (i < 30) {
      int s2 = cur + 2; if (s2 >= 3) s2 -= 3;
      ATTN_STAGE((i + 2) * 64, s2)
    }
    ATTN_BODY
    ++cur; if (cur == 3) cur = 0;
  }
  // peeled final iteration: drain
  BAR_VM(0)
  ATTN_BODY

#undef ATTN_STAGE
#undef ATTN_BODY

  // ---- merge l across the 4 wh-quarters ----
#pragma unroll
  for (int j = 0; j < 4; ++j) {
    float r = lsum[j];
    r += __shfl_xor(r, 1);
    r += __shfl_xor(r, 2);
    r += __shfl_xor(r, 4);
    r += __shfl_xor(r, 8);
    lsum[j] = r;
  }
  if (lr == 0) {
#pragma unroll
    for (int j = 0; j < 4; ++j) lb[(wq * 4 + wh) * 16 + 4 * g + j] = lsum[j];
  }
  __syncthreads();

  float inv[4];
#pragma unroll
  for (int j = 0; j < 4; ++j) {
    int row = 4 * g + j;
    float l = lb[(wq * 4 + 0) * 16 + row] + lb[(wq * 4 + 1) * 16 + row] +
              lb[(wq * 4 + 2) * 16 + row] + lb[(wq * 4 + 3) * 16 + row];
    inv[j] = 1.0f / l;
  }
  float* op = out + (b * T_DIM + t0 + wq * 16) * 128;
#pragma unroll
  for (int hf = 0; hf < 2; ++hf)
#pragma unroll
    for (int j = 0; j < 4; ++j)
      op[(4 * g + j) * 128 + wh * 32 + hf * 16 + lr] = of[hf][j] * inv[j];
}

// ---------- launcher ----------
extern "C" void kernel_launch(void* const* d_in, const int* in_sizes, int n_in,
                              void* d_out, int out_size, void* d_ws,
                              size_t ws_size, hipStream_t stream) {
  const float* x  = (const float*)d_in[0];
  const float* Wk = (const float*)d_in[1];
  const float* Wq = (const float*)d_in[2];
  const float* Wv = (const float*)d_in[3];
  float* out = (float*)d_out;

  char* ws = (char*)d_ws;
  ushort* Wt  = (ushort*)ws;                       // 0.75 MB
  ushort* qb  = (ushort*)(ws + (1u << 20));        // 2 MB
  ushort* kb  = (ushort*)(ws + 3u * (1u << 20));   // 2 MB
  ushort* vtb = (ushort*)(ws + 5u * (1u << 20));   // 2 MB

  (void)hipFuncSetAttribute(reinterpret_cast<const void*>(&attn),
                            hipFuncAttributeMaxDynamicSharedMemorySize, 103424);

  wconv<<<dim3(16, 2, 3), dim3(256), 0, stream>>>(Wq, Wk, Wv, Wt);
  proj<<<dim3(256, 3), dim3(256), 0, stream>>>(x, Wt, qb, kb, vtb);
  attn<<<dim3(64, 4), dim3(512), 103424, stream>>>(qb, kb, vtb, out);
}

// Round 11
// 55.429 us; speedup vs baseline: 1.5398x; 1.1711x over previous
//
#include <hip/hip_runtime.h>
#include <hip/hip_bf16.h>

typedef float  f32x4 __attribute__((ext_vector_type(4)));
typedef float  f32x8 __attribute__((ext_vector_type(8)));
typedef short  s8v   __attribute__((ext_vector_type(8)));
typedef __bf16 b8v   __attribute__((ext_vector_type(8)));
typedef unsigned int u32;
typedef unsigned short ushort;

#define T_DIM  2048
#define C_DIM  1024

// ---------- helpers ----------

typedef const __attribute__((address_space(1))) u32 gu32;
typedef __attribute__((address_space(3))) u32 lu32;

// async global->LDS, 16B per lane; LDS dest = uniform base + lane*16
static __device__ __forceinline__ void glds16(const void* g, void* l) {
  __builtin_amdgcn_global_load_lds((gu32*)g, (lu32*)l, 16, 0, 0);
}

static __device__ __forceinline__ b8v ldb8(const ushort* p) {
  return __builtin_bit_cast(b8v, *reinterpret_cast<const s8v*>(p));
}

static __device__ __forceinline__ b8v cvt8(f32x8 v) {
  b8v r;
#pragma unroll
  for (int i = 0; i < 8; ++i) r[i] = (__bf16)v[i];
  return r;
}

static __device__ __forceinline__ ushort bfu(float f) {
  __bf16 h = (__bf16)f;
  return __builtin_bit_cast(ushort, h);
}

static __device__ __forceinline__ f32x4 mfma16(b8v a, b8v b, f32x4 c) {
  return __builtin_amdgcn_mfma_f32_16x16x32_bf16(a, b, c, 0, 0, 0);
}

// raw barrier with counted vmcnt
#define BAR_VM(N)                                                        \
  asm volatile("s_waitcnt vmcnt(" #N ") lgkmcnt(0)" ::: "memory");       \
  __builtin_amdgcn_s_barrier();                                          \
  asm volatile("" ::: "memory");

// ---------- kernel 0: W -> Wt bf16 transposed [3][128][1024] ----------
__global__ __launch_bounds__(256) void wconv(const float* __restrict__ Wq,
                                             const float* __restrict__ Wk,
                                             const float* __restrict__ Wv,
                                             ushort* __restrict__ Wt) {
  __shared__ float lds[64][65];
  const int m  = blockIdx.z;
  const int c0 = blockIdx.x * 64;
  const int h0 = blockIdx.y * 64;
  const float* W = (m == 0) ? Wq : (m == 1) ? Wk : Wv;

  const int cl = threadIdx.x >> 4;
  const int h4 = (threadIdx.x & 15) * 4;
#pragma unroll
  for (int i = 0; i < 4; ++i) {
    int c = cl + i * 16;
    float4 v = *reinterpret_cast<const float4*>(W + (c0 + c) * 128 + h0 + h4);
    lds[c][h4] = v.x; lds[c][h4 + 1] = v.y;
    lds[c][h4 + 2] = v.z; lds[c][h4 + 3] = v.w;
  }
  __syncthreads();
  const int hl = threadIdx.x >> 2;
  const int cs = (threadIdx.x & 3) * 16;
  s8v o0, o1;
#pragma unroll
  for (int i = 0; i < 8; ++i) o0[i] = (short)bfu(lds[cs + i][hl]);
#pragma unroll
  for (int i = 0; i < 8; ++i) o1[i] = (short)bfu(lds[cs + 8 + i][hl]);
  ushort* dst = Wt + (m * 128 + h0 + hl) * C_DIM + c0 + cs;
  *reinterpret_cast<s8v*>(dst) = o0;
  *reinterpret_cast<s8v*>(dst + 8) = o1;
}

// ---------- kernel 1: q/k/v projection (verified round-6 version) ----------
__global__ __launch_bounds__(256) void proj(const float* __restrict__ x,
                                            const ushort* __restrict__ Wt,
                                            ushort* __restrict__ q,
                                            ushort* __restrict__ k,
                                            ushort* __restrict__ vt) {
  __shared__ __align__(16) ushort Ab[2][32 * 72];
  __shared__ __align__(16) ushort Bb[2][128 * 64];
  __shared__ __align__(16) ushort stage[5120];

  const int t   = threadIdx.x;
  const int w   = t >> 6;
  const int lid = t & 63;
  const int lr  = lid & 15;
  const int g   = lid >> 4;
  const int wr  = w >> 1;
  const int wc  = w & 1;
  const int m   = blockIdx.y;
  const int r0  = blockIdx.x * 32;

  const int arow = t >> 3;
  const int acol = (t & 7) * 8;
  const float* ag = x + (r0 + arow) * C_DIM + acol;

  const int bswz = (((lid & 7) ^ (lid >> 3)) << 4);
  const char* bg = (const char*)(Wt + m * 128 * C_DIM);

  f32x4 acc[4] = {};

#pragma unroll
  for (int j = 0; j < 4; ++j) {
    int h = j * 32 + w * 8 + (lid >> 3);
    glds16(bg + h * 2048 + bswz, (char*)&Bb[0][0] + j * 4096 + w * 1024);
  }
  {
    f32x8 av = *reinterpret_cast<const f32x8*>(ag);
    b8v ac = cvt8(av);
    *reinterpret_cast<s8v*>(&Ab[0][arow * 72 + acol]) =
        __builtin_bit_cast(s8v, ac);
  }
  __syncthreads();

  int cur = 0;
#pragma unroll 1
  for (int i = 0; i < 16; ++i) {
    const int nxt = cur ^ 1;
    f32x8 an;
    if (i < 15) {
      const int kk = (i + 1) * 64;
#pragma unroll
      for (int j = 0; j < 4; ++j) {
        int h = j * 32 + w * 8 + (lid >> 3);
        glds16(bg + h * 2048 + kk * 2 + bswz,
               (char*)&Bb[nxt][0] + j * 4096 + w * 1024);
      }
      an = *reinterpret_cast<const f32x8*>(ag + kk);
    }

#pragma unroll
    for (int kk2 = 0; kk2 < 2; ++kk2) {
      b8v af = ldb8(&Ab[cur][(wr * 16 + lr) * 72 + kk2 * 32 + g * 8]);
#pragma unroll
      for (int cn = 0; cn < 4; ++cn) {
        int h = wc * 64 + cn * 16 + lr;
        int inner = (kk2 * 64 + g * 16) ^ ((h & 7) << 4);
        b8v bf = ldb8(
            (const ushort*)((const char*)&Bb[cur][h * 64] + inner));
        acc[cn] = mfma16(af, bf, acc[cn]);
      }
    }

    if (i < 15) {
      b8v anc = cvt8(an);
      *reinterpret_cast<s8v*>(&Ab[nxt][arow * 72 + acol]) =
          __builtin_bit_cast(s8v, anc);
    }
    __syncthreads();
    cur = nxt;
  }

  if (m < 2) {
#pragma unroll
    for (int cn = 0; cn < 4; ++cn)
#pragma unroll
      for (int j = 0; j < 4; ++j)
        stage[(wr * 16 + 4 * g + j) * 136 + wc * 64 + cn * 16 + lr] =
            bfu(acc[cn][j]);
    __syncthreads();
    ushort* dst = (m == 0) ? q : k;
#pragma unroll
    for (int c = 0; c < 2; ++c) {
      int chunk = c * 256 + t;
      int row = chunk >> 4, col8 = chunk & 15;
      s8v v8 = *reinterpret_cast<const s8v*>(&stage[row * 136 + col8 * 8]);
      *reinterpret_cast<s8v*>(&dst[(r0 + row) * 128 + col8 * 8]) = v8;
    }
  } else {
#pragma unroll
    for (int cn = 0; cn < 4; ++cn)
#pragma unroll
      for (int j = 0; j < 4; ++j)
        stage[(wc * 64 + cn * 16 + lr) * 40 + wr * 16 + 4 * g + j] =
            bfu(acc[cn][j]);
    __syncthreads();
    int b = blockIdx.x >> 6;
    int tbase = (blockIdx.x & 63) * 32;
#pragma unroll
    for (int c = 0; c < 2; ++c) {
      int chunk = c * 256 + t;
      int h = chunk >> 2, t8 = chunk & 3;
      s8v v8 = *reinterpret_cast<const s8v*>(&stage[h * 40 + t8 * 8]);
      *reinterpret_cast<s8v*>(&vt[(b * 128 + h) * T_DIM + tbase + t8 * 8]) = v8;
    }
  }
}

// ---------- kernel 2: flash attention, swapped-QK^T, P in registers ----------
// grid (64, 4) x 256 thr (4 waves). Block: 32 q-rows, kv sweeps 2048 in 32
// steps of 64. Waves = (wh in {0,1}: h-64 half) x (wk in {0,1}: kv-32 half).
// Swapped QK^T (A=K, B=Q) with permuted K rows (row lr -> 8*(lr>>2)+(lr&3)+4t)
// makes the two kv-16 tile outputs pack IDENTITY into the PV A-frag
// (kv = 8g+i): exp -> bf16 pack -> PV straight from registers. No P-LDS,
// one barrier/iter. K/V staged via 3-buffer 2-deep counted-vmcnt glds
// (round-10-verified protocol). O merged across wk once at the end.
__global__ __launch_bounds__(256) void attn(const ushort* __restrict__ q,
                                            const ushort* __restrict__ k,
                                            const ushort* __restrict__ vt,
                                            float* __restrict__ out) {
  extern __shared__ __align__(16) char smem[];  // 3 x (K 16K + V 16K) = 96 KB

  const int t   = threadIdx.x;
  const int w   = t >> 6;
  const int lid = t & 63;
  const int lr  = lid & 15;
  const int g   = lid >> 4;
  const int wh  = w >> 1;   // h-64 half
  const int wk  = w & 1;    // kv-32 half
  const int b   = blockIdx.y;
  const int t0  = blockIdx.x * 32;

  // hoist Q fragments (B-operand): q-32, two q-16 groups
  const ushort* qp = q + (b * T_DIM + t0) * 128;
  b8v aq[2][4];
#pragma unroll
  for (int qg = 0; qg < 2; ++qg)
#pragma unroll
    for (int kf = 0; kf < 4; ++kf)
      aq[qg][kf] = ldb8(&qp[(qg * 16 + lr) * 128 + kf * 32 + g * 8]);

  // staging source pointers (lane-constant, minus the kv0 term)
  const char* kgb = (const char*)(k + b * T_DIM * 128);
  const char* vgb = (const char*)(vt + b * 128 * T_DIM);
  const char* ksrc[4];
  const char* vsrc[4];
#pragma unroll
  for (int j = 0; j < 4; ++j) {
    ksrc[j] = kgb + (16 * w + 4 * j + (lid >> 4)) * 256 +
              (((lid & 15) ^ (4 * j + (lid >> 4))) << 4);
    vsrc[j] = vgb + ((w * 4 + j) * 8 + (lid >> 3)) * 4096 +
              (((lid & 7) ^ (lid >> 3)) << 4);
  }

  // compute-side LDS byte offsets (within a buffer)
  const int rbase = wk * 32 + 8 * (lr >> 2) + (lr & 3);
  int koff[2][4], voff[4];
#pragma unroll
  for (int tt = 0; tt < 2; ++tt)
#pragma unroll
    for (int kf = 0; kf < 4; ++kf)
      koff[tt][kf] = (rbase + 4 * tt) * 256 +
                     (((kf * 4 + g) ^ ((rbase + 4 * tt) & 15)) << 4);
#pragma unroll
  for (int hf = 0; hf < 4; ++hf)
    voff[hf] = 16384 + (wh * 64 + hf * 16 + lr) * 128 +
               (((wk * 4 + g) ^ (lr & 7)) << 4);

  f32x4 of[2][4] = {};   // [qg][hf]
  float lsum[2] = {0.0f, 0.0f};
  const float scale = 0.08838834764831845f;  // 128^-0.5

#define ATTN_STAGE(KV0, BUF)                                              \
  _Pragma("unroll") for (int j = 0; j < 4; ++j)                           \
      glds16(ksrc[j] + (KV0) * 256,                                       \
             smem + (BUF) * 32768 + (w * 4 + j) * 1024);                  \
  _Pragma("unroll") for (int j = 0; j < 4; ++j)                           \
      glds16(vsrc[j] + (KV0) * 2,                                         \
             smem + (BUF) * 32768 + 16384 + (w * 4 + j) * 1024);

#define ATTN_BODY(BUF)                                                    \
  {                                                                       \
    const char* Kb = smem + (BUF) * 32768;                                \
    b8v kf0[4], kf1[4], vf[4];                                            \
    _Pragma("unroll") for (int kf = 0; kf < 4; ++kf)                      \
        kf0[kf] = ldb8((const ushort*)(Kb + koff[0][kf]));                \
    _Pragma("unroll") for (int kf = 0; kf < 4; ++kf)                      \
        kf1[kf] = ldb8((const ushort*)(Kb + koff[1][kf]));                \
    _Pragma("unroll") for (int hf = 0; hf < 4; ++hf)                      \
        vf[hf] = ldb8((const ushort*)(Kb + voff[hf]));                    \
    f32x4 s0[2] = {}, s1[2] = {};                                         \
    __builtin_amdgcn_s_setprio(1);                                        \
    _Pragma("unroll") for (int qg = 0; qg < 2; ++qg)                      \
        _Pragma("unroll") for (int kf = 0; kf < 4; ++kf) {                \
      s0[qg] = mfma16(kf0[kf], aq[qg][kf], s0[qg]);                       \
      s1[qg] = mfma16(kf1[kf], aq[qg][kf], s1[qg]);                       \
    }                                                                     \
    __builtin_amdgcn_s_setprio(0);                                        \
    b8v pk[2];                                                            \
    _Pragma("unroll") for (int qg = 0; qg < 2; ++qg) {                    \
      float p0 = __expf(s0[qg][0] * scale - 4.0f);                        \
      float p1 = __expf(s0[qg][1] * scale - 4.0f);                        \
      float p2 = __expf(s0[qg][2] * scale - 4.0f);                        \
      float p3 = __expf(s0[qg][3] * scale - 4.0f);                        \
      float p4 = __expf(s1[qg][0] * scale - 4.0f);                        \
      float p5 = __expf(s1[qg][1] * scale - 4.0f);                        \
      float p6 = __expf(s1[qg][2] * scale - 4.0f);                        \
      float p7 = __expf(s1[qg][3] * scale - 4.0f);                        \
      lsum[qg] += ((p0 + p1) + (p2 + p3)) + ((p4 + p5) + (p6 + p7));      \
      pk[qg][0] = (__bf16)p0; pk[qg][1] = (__bf16)p1;                     \
      pk[qg][2] = (__bf16)p2; pk[qg][3] = (__bf16)p3;                     \
      pk[qg][4] = (__bf16)p4; pk[qg][5] = (__bf16)p5;                     \
      pk[qg][6] = (__bf16)p6; pk[qg][7] = (__bf16)p7;                     \
    }                                                                     \
    __builtin_amdgcn_s_setprio(1);                                        \
    _Pragma("unroll") for (int qg = 0; qg < 2; ++qg)                      \
        _Pragma("unroll") for (int hf = 0; hf < 4; ++hf)                  \
            of[qg][hf] = mfma16(pk[qg], vf[hf], of[qg][hf]);              \
    __builtin_amdgcn_s_setprio(0);                                        \
  }

  // ---- prologue: 2 stages in flight ----
  ATTN_STAGE(0, 0)
  ATTN_STAGE(64, 1)

  int cur = 0;
#pragma unroll 1
  for (int i = 0; i < 31; ++i) {
    BAR_VM(8)  // own stage(i) done; stage(i+1) in flight; then barrier
    if (i < 30) {
      int nb = cur + 2; if (nb >= 3) nb -= 3;
      ATTN_STAGE((i + 2) * 64, nb)
    }
    ATTN_BODY(cur)
    ++cur; if (cur == 3) cur = 0;
  }
  BAR_VM(0)
  ATTN_BODY(cur)

#undef ATTN_STAGE
#undef ATTN_BODY

  // ---- reduce lsum over the 4 g-groups (kv slices) ----
#pragma unroll
  for (int qg = 0; qg < 2; ++qg) {
    float r = lsum[qg];
    r += __shfl_xor(r, 16);
    r += __shfl_xor(r, 32);
    lsum[qg] = r;
  }

  // ---- merge across wk via LDS (aliases staging buffers; loop is done) ----
  float* lb = (float*)smem;           // [wk][qg][16]
  float* ob = (float*)(smem + 256);   // [wh][32 q][64 h]
  __syncthreads();
  if (wh == 0 && g == 0) {
    lb[wk * 32 + 0 * 16 + lr] = lsum[0];
    lb[wk * 32 + 1 * 16 + lr] = lsum[1];
  }
  if (wk == 1) {
#pragma unroll
    for (int qg = 0; qg < 2; ++qg)
#pragma unroll
      for (int hf = 0; hf < 4; ++hf)
#pragma unroll
        for (int j = 0; j < 4; ++j)
          ob[(wh * 32 + qg * 16 + 4 * g + j) * 64 + hf * 16 + lr] =
              of[qg][hf][j];
  }
  __syncthreads();
  if (wk == 0) {
    float inv[2][4];
#pragma unroll
    for (int qg = 0; qg < 2; ++qg)
#pragma unroll
      for (int j = 0; j < 4; ++j)
        inv[qg][j] = 1.0f / (lb[qg * 16 + 4 * g + j] +
                             lb[32 + qg * 16 + 4 * g + j]);
#pragma unroll
    for (int qg = 0; qg < 2; ++qg)
#pragma unroll
      for (int hf = 0; hf < 4; ++hf)
#pragma unroll
        for (int j = 0; j < 4; ++j) {
          int qrow = qg * 16 + 4 * g + j;
          float val = of[qg][hf][j] + ob[(wh * 32 + qrow) * 64 + hf * 16 + lr];
          out[(b * T_DIM + t0 + qrow) * 128 + wh * 64 + hf * 16 + lr] =
              val * inv[qg][j];
        }
  }
}

// ---------- launcher ----------
extern "C" void kernel_launch(void* const* d_in, const int* in_sizes, int n_in,
                              void* d_out, int out_size, void* d_ws,
                              size_t ws_size, hipStream_t stream) {
  const float* x  = (const float*)d_in[0];
  const float* Wk = (const float*)d_in[1];
  const float* Wq = (const float*)d_in[2];
  const float* Wv = (const float*)d_in[3];
  float* out = (float*)d_out;

  char* ws = (char*)d_ws;
  ushort* Wt  = (ushort*)ws;                       // 0.75 MB
  ushort* qb  = (ushort*)(ws + (1u << 20));        // 2 MB
  ushort* kb  = (ushort*)(ws + 3u * (1u << 20));   // 2 MB
  ushort* vtb = (ushort*)(ws + 5u * (1u << 20));   // 2 MB

  (void)hipFuncSetAttribute(reinterpret_cast<const void*>(&attn),
                            hipFuncAttributeMaxDynamicSharedMemorySize, 98304);

  wconv<<<dim3(16, 2, 3), dim3(256), 0, stream>>>(Wq, Wk, Wv, Wt);
  proj<<<dim3(256, 3), dim3(256), 0, stream>>>(x, Wt, qb, kb, vtb);
  attn<<<dim3(64, 4), dim3(256), 98304, stream>>>(qb, kb, vtb, out);
}